// Round 4
// baseline (115.442 us; speedup 1.0000x reference)
//
#include <hip/hip_runtime.h>

// RelativePositionEncoding, N=1024, C=128. out[i,j,c] =
//   (Wpos[dp,c] + Wtok[dt,c] + same_ent*Went[c] + Wchain[dc,c]) * m_i*m_j
// Structure exploit: asym_id has ~8 chains -> ~87% of pairs are cross-chain,
// where dp=65, dt=65, dc=5 are constant => per-thread register-cached
// S_diff = Wpos[65]+Wtok[65]+Wchain[5]. Same-chain: dc=2 (a_i==a_j -> d=0),
// only 2 LDS row reads. 32 lanes per pair -> 1 KB contiguous per wave store.

#define N_TOK 1024
#define C_PAIR 128
#define NR 66            // 2*R_MAX + 2
#define W_COLS 139       // 2*NR + NS + 1
#define ROW_ENT 132
#define ROW_CH  133      // chain rows 133..138

typedef float f32x4 __attribute__((ext_vector_type(4)));
typedef int   i32x4 __attribute__((ext_vector_type(4)));

__global__ __launch_bounds__(256, 4)
void pack_kernel(const int* __restrict__ ri, const int* __restrict__ ti,
                 const int* __restrict__ ai, const int* __restrict__ ei,
                 const float* __restrict__ mask, i32x4* __restrict__ pk) {
    int j = blockIdx.x * blockDim.x + threadIdx.x;
    if (j < N_TOK) {
        i32x4 p;
        p.x = ri[j];
        p.y = ti[j];
        p.z = (ai[j] << 16) | (ei[j] & 0xffff);
        p.w = __float_as_int(mask[j]);
        pk[j] = p;
    }
}

template<bool USE_PK>
__global__ __launch_bounds__(1024, 8)
void relpos_kernel(const int* __restrict__ ri, const int* __restrict__ ti,
                   const int* __restrict__ ai, const int* __restrict__ ei,
                   const float* __restrict__ mask, const float* __restrict__ W,
                   const i32x4* __restrict__ pk, float* __restrict__ out) {
    __shared__ float wt[W_COLS * C_PAIR];   // wt[k][c] = W[c][k]; 71.2 KB

    for (int idx = threadIdx.x; idx < C_PAIR * W_COLS; idx += blockDim.x) {
        int c = idx / W_COLS;                // coalesced read, magic-mul
        int k = idx - c * W_COLS;
        wt[k * C_PAIR + c] = W[idx];
    }
    __syncthreads();

    const int c4 = threadIdx.x & 31;         // float4 slot within the 128 channels
    const int jg = threadIdx.x >> 5;         // 32 pair-groups per block

    const f32x4* wt4 = (const f32x4*)wt;
    // register-cached rows (each thread holds its own float4 slice)
    f32x4 went  = wt4[ROW_ENT * 32 + c4];
    f32x4 wc2   = wt4[(ROW_CH + 2) * 32 + c4];
    f32x4 sdiff = wt4[65 * 32 + c4] + wt4[131 * 32 + c4] + wt4[(ROW_CH + 5) * 32 + c4];

    for (int i = blockIdx.x; i < N_TOK; i += gridDim.x) {
        int r_i, t_i, a_i, e_i; float m_i;
        if (USE_PK) {
            i32x4 p = pk[i];
            r_i = p.x; t_i = p.y; a_i = p.z >> 16; e_i = p.z & 0xffff;
            m_i = __int_as_float(p.w);
        } else {
            r_i = ri[i]; t_i = ti[i]; a_i = ai[i]; e_i = ei[i]; m_i = mask[i];
        }
        f32x4* __restrict__ orow = (f32x4*)(out + (size_t)i * (N_TOK * C_PAIR));

        #pragma unroll 4
        for (int j = jg; j < N_TOK; j += 32) {
            int r_j, t_j, a_j, e_j; float m_j;
            if (USE_PK) {
                i32x4 p = pk[j];
                r_j = p.x; t_j = p.y; a_j = p.z >> 16; e_j = p.z & 0xffff;
                m_j = __int_as_float(p.w);
            } else {
                r_j = ri[j]; t_j = ti[j]; a_j = ai[j]; e_j = ei[j]; m_j = mask[j];
            }
            float mm = m_i * m_j;
            float f  = (e_i == e_j) ? 1.0f : 0.0f;

            f32x4 v;
            if (a_i == a_j) {   // same chain (~12.5%): dc=2; 2 LDS row reads
                int dp = min(max(r_j - r_i + 32, 0), 64);
                int r2 = (r_i == r_j) ? (NR + min(max(t_j - t_i + 32, 0), 64))
                                      : 131;   // Wtok[65]
                v = wt4[dp * 32 + c4] + wt4[r2 * 32 + c4] + wc2;
            } else {            // cross chain (~87.5%): zero LDS reads
                v = sdiff;
            }
            v = (v + f * went) * mm;
            orow[j * 32 + c4] = v;   // wave: 1 KB contiguous
        }
    }
}

extern "C" void kernel_launch(void* const* d_in, const int* in_sizes, int n_in,
                              void* d_out, int out_size, void* d_ws, size_t ws_size,
                              hipStream_t stream) {
    const int*   ri   = (const int*)d_in[0];
    const int*   ti   = (const int*)d_in[1];
    const int*   ai   = (const int*)d_in[2];
    const int*   ei   = (const int*)d_in[3];
    const float* mask = (const float*)d_in[4];
    const float* W    = (const float*)d_in[5];
    float*       out  = (float*)d_out;

    const int threads = 1024;
    const int blocks  = 512;    // 2 blocks/CU (71.2 KB LDS), 2 i-rows/block

    if (ws_size >= (size_t)N_TOK * sizeof(i32x4) && d_ws != nullptr) {
        i32x4* pk = (i32x4*)d_ws;
        pack_kernel<<<4, 256, 0, stream>>>(ri, ti, ai, ei, mask, pk);
        relpos_kernel<true><<<blocks, threads, 0, stream>>>(ri, ti, ai, ei, mask,
                                                            W, pk, out);
    } else {
        relpos_kernel<false><<<blocks, threads, 0, stream>>>(ri, ti, ai, ei, mask,
                                                             W, nullptr, out);
    }
}